// Round 14
// baseline (341.083 us; speedup 1.0000x reference)
//
#include <hip/hip_runtime.h>
#include <hip/hip_bf16.h>

#define BB 4
#define NN 16384
#define CC 384
#define DD 192
#define MM 1024

typedef __attribute__((ext_vector_type(8))) short short8;
typedef __attribute__((ext_vector_type(4))) float f32x4;
typedef unsigned short u16;

__device__ __forceinline__ float4 ld4(const float* p) { return *reinterpret_cast<const float4*>(p); }

__device__ __forceinline__ u16 bf16r(float f) {
    unsigned int u = __float_as_uint(f);
    return (u16)((u + 0x7FFFu + ((u >> 16) & 1u)) >> 16);
}
__device__ __forceinline__ unsigned int pk2(float a, float b) {
    return (unsigned int)bf16r(a) | ((unsigned int)bf16r(b) << 16);
}
// packed RNE f32x2 -> bf16x2 (lowers to v_cvt_pk_bf16_f32)
__device__ __forceinline__ unsigned int pk2c(float a, float b) {
    __hip_bfloat162 h = __float22bfloat162_rn(make_float2(a, b));
    union { __hip_bfloat162 h2; unsigned int u; } c; c.h2 = h; return c.u;
}
__device__ __forceinline__ short8 as_s8(uint4 v) {
    union { uint4 u; short8 s; } x; x.u = v; return x.s;
}
__device__ __forceinline__ f32x4 mfma16(short8 a, short8 b, f32x4 c) {
    return __builtin_amdgcn_mfma_f32_16x16x32_bf16(a, b, c, 0, 0, 0);
}
// async global->LDS, 16B per lane; LDS dest = wave-uniform base + lane*16
__device__ __forceinline__ void gload16(const void* g, void* l) {
    __builtin_amdgcn_global_load_lds(
        (const __attribute__((address_space(1))) void*)g,
        (__attribute__((address_space(3))) void*)l, 16, 0, 0);
}

// ---------------- K0a: proj_w fp32 -> bf16 ----------------
__global__ __launch_bounds__(256) void k_prep(const float* __restrict__ pw, u16* __restrict__ pwb)
{
    int i = blockIdx.x * 256 + threadIdx.x;
    float4 v = ld4(&pw[i * 4]);
    uint2 o; o.x = pk2(v.x, v.y); o.y = pk2(v.z, v.w);
    reinterpret_cast<uint2*>(pwb)[i] = o;
}

// ---------------- K0b: conv_w -> cwb[k8][o][8] bf16, k = px*192 + i ----------------
__global__ __launch_bounds__(256) void k_prepw(const float* __restrict__ cw, u16* __restrict__ cwb)
{
    int idx = blockIdx.x * 256 + threadIdx.x;
    int k8 = idx / 192, o = idx % 192;
    int px = k8 / 24;
    int i0 = (k8 % 24) * 8;
    float f[8];
    #pragma unroll
    for (int e = 0; e < 8; ++e) f[e] = cw[(size_t)(o * 192 + i0 + e) * 16 + px];
    uint4 v = make_uint4(pk2(f[0], f[1]), pk2(f[2], f[3]), pk2(f[4], f[5]), pk2(f[6], f[7]));
    reinterpret_cast<uint4*>(cwb)[idx] = v;
}

// ---------------- K1: conv via MFMA, px-split x2 -> partials Cp2[s][P][o] ----------------
__global__ __launch_bounds__(256) void k_conv(const float* __restrict__ x,
                                              const u16* __restrict__ cwb,
                                              float* __restrict__ Cp2)
{
    const int bid = blockIdx.x;
    const int s = bid >> 8, pt = bid & 255;
    const int b = pt >> 6;
    const int m0 = (pt & 63) * 16;
    const int P0 = pt * 16;
    const int t = threadIdx.x;
    const int l = t & 63, w = t >> 6;
    const int l15 = l & 15, l4 = l >> 4;
    const int o0 = w * 48;

    const int m = m0 + l15;
    const int ph = m >> 5, pw_ = m & 31;
    const float* xp = x + ((size_t)(b * NN) + ph * 512 + pw_ * 4) * CC + DD;

    f32x4 acc[3];
    #pragma unroll
    for (int ft = 0; ft < 3; ++ft) acc[ft] = (f32x4){0.f, 0.f, 0.f, 0.f};

    for (int kt = 0; kt < 48; ++kt) {
        const int px = s * 8 + kt / 6;
        const int i0 = (kt % 6) * 32;
        const int kh = px >> 2, kw = px & 3;
        const float* src = xp + (size_t)(kh * 128 + kw) * CC + i0 + l4 * 8;
        float4 v0 = ld4(src), v1 = ld4(src + 4);
        short8 av = as_s8(make_uint4(pk2(v0.x, v0.y), pk2(v0.z, v0.w), pk2(v1.x, v1.y), pk2(v1.z, v1.w)));
        const int k8g = px * 24 + (kt % 6) * 4 + l4;
        #pragma unroll
        for (int ft = 0; ft < 3; ++ft) {
            int o = o0 + ft * 16 + l15;
            short8 bv = as_s8(*reinterpret_cast<const uint4*>(cwb + (size_t)(k8g * 192 + o) * 8));
            acc[ft] = mfma16(av, bv, acc[ft]);
        }
    }
    #pragma unroll
    for (int ft = 0; ft < 3; ++ft)
        #pragma unroll
        for (int i = 0; i < 4; ++i)
            Cp2[(size_t)(s * 4096 + P0 + l4 * 4 + i) * 192 + o0 + ft * 16 + l15] = acc[ft][i];
}

// ---------------- K1b: reduce px-splits + bias -> x2cT[m][d], x2cM[d][m] bf16 ----------------
__global__ __launch_bounds__(256) void k_convred(const float* __restrict__ Cp2,
                                                 const float* __restrict__ cb,
                                                 u16* __restrict__ x2cT,
                                                 u16* __restrict__ x2cM)
{
    __shared__ u16 T[64 * 194];
    const int bid = blockIdx.x;
    const int b = bid >> 4, mc = bid & 15;
    const int P0 = b * 1024 + mc * 64;
    const int t = threadIdx.x;
    #pragma unroll
    for (int j = 0; j < 12; ++j) {
        int idx = j * 256 + t;
        int row = idx / 48, c4 = idx % 48;
        float4 v0 = ld4(&Cp2[(size_t)(P0 + row) * 192 + c4 * 4]);
        float4 v1 = ld4(&Cp2[(size_t)(4096 + P0 + row) * 192 + c4 * 4]);
        float4 bb = ld4(&cb[c4 * 4]);
        float r0 = v0.x + v1.x + bb.x, r1 = v0.y + v1.y + bb.y;
        float r2 = v0.z + v1.z + bb.z, r3 = v0.w + v1.w + bb.w;
        u16 h0 = bf16r(r0), h1 = bf16r(r1), h2 = bf16r(r2), h3 = bf16r(r3);
        uint2 ov; ov.x = (unsigned int)h0 | ((unsigned int)h1 << 16);
        ov.y = (unsigned int)h2 | ((unsigned int)h3 << 16);
        *reinterpret_cast<uint2*>(x2cT + (size_t)(P0 + row) * 192 + c4 * 4) = ov;
        T[row * 194 + c4 * 4 + 0] = h0; T[row * 194 + c4 * 4 + 1] = h1;
        T[row * 194 + c4 * 4 + 2] = h2; T[row * 194 + c4 * 4 + 3] = h3;
    }
    __syncthreads();
    #pragma unroll
    for (int j = 0; j < 6; ++j) {
        int u = j * 256 + t;
        int o = u >> 3, m8 = (u & 7) * 8;
        unsigned int pk[4];
        #pragma unroll
        for (int q = 0; q < 4; ++q) {
            u16 a = T[(m8 + q * 2) * 194 + o];
            u16 c = T[(m8 + q * 2 + 1) * 194 + o];
            pk[q] = (unsigned int)a | ((unsigned int)c << 16);
        }
        *reinterpret_cast<uint4*>(x2cM + ((size_t)(b * DD + o) * MM) + mc * 64 + m8) =
            make_uint4(pk[0], pk[1], pk[2], pk[3]);
    }
}

// ---------------- K2: S partials via bf16 hi/lo MFMA ----------------
__global__ __launch_bounds__(512) void k_S(const float* __restrict__ x, float* __restrict__ Sp,
                                           int KS, int nkt)
{
    __shared__ char LS[384 * 128];
    const int bid = blockIdx.x;
    const int b = bid / KS, ks = bid % KS;
    const int n0 = ks * (NN / KS);
    const int t = threadIdx.x;
    const int l = t & 63, w = t >> 6;
    const int rg = w >> 2, cs = w & 3;
    const int l15 = l & 15, l4 = l >> 4, key = (l15 & 7) << 4;

    const int c0 = (t & 127) * 3;
    const int krow = t >> 7;

    f32x4 acc[6][3];
    #pragma unroll
    for (int dt = 0; dt < 6; ++dt)
        #pragma unroll
        for (int et = 0; et < 3; ++et) acc[dt][et] = (f32x4){0.f, 0.f, 0.f, 0.f};

    for (int kt = 0; kt < nkt; ++kt) {
        __syncthreads();
        #pragma unroll
        for (int i = 0; i < 8; ++i) {
            int k = i * 4 + krow;
            const float* src = &x[(size_t)(b * NN + n0 + kt * 32 + k) * CC + c0];
            #pragma unroll
            for (int j = 0; j < 3; ++j) {
                int c = c0 + j;
                float v = src[j];
                u16 hi = bf16r(v);
                float hif = __uint_as_float(((unsigned int)hi) << 16);
                u16 lo = bf16r(v - hif);
                int base = c * 128;
                int ck = (c & 7) << 4;
                *reinterpret_cast<u16*>(LS + base + ((k * 2) ^ ck)) = hi;
                *reinterpret_cast<u16*>(LS + base + ((64 + k * 2) ^ ck)) = lo;
            }
        }
        __syncthreads();
        short8 bf[3][2];
        #pragma unroll
        for (int et = 0; et < 3; ++et) {
            int c = 192 + cs * 48 + et * 16 + l15;
            #pragma unroll
            for (int hl = 0; hl < 2; ++hl)
                bf[et][hl] = *reinterpret_cast<const short8*>(LS + c * 128 + ((hl * 64 + l4 * 16) ^ key));
        }
        #pragma unroll
        for (int dt = 0; dt < 6; ++dt) {
            int c = rg * 96 + dt * 16 + l15;
            short8 ah = *reinterpret_cast<const short8*>(LS + c * 128 + ((l4 * 16) ^ key));
            short8 al = *reinterpret_cast<const short8*>(LS + c * 128 + ((64 + l4 * 16) ^ key));
            #pragma unroll
            for (int et = 0; et < 3; ++et) {
                acc[dt][et] = mfma16(ah, bf[et][0], acc[dt][et]);
                acc[dt][et] = mfma16(ah, bf[et][1], acc[dt][et]);
                acc[dt][et] = mfma16(al, bf[et][0], acc[dt][et]);
            }
        }
    }
    float* dst = Sp + (size_t)(ks * BB + b) * 36864;
    #pragma unroll
    for (int dt = 0; dt < 6; ++dt)
        #pragma unroll
        for (int et = 0; et < 3; ++et) {
            int e = cs * 48 + et * 16 + l15;
            #pragma unroll
            for (int i = 0; i < 4; ++i) {
                int d = rg * 96 + dt * 16 + l4 * 4 + i;
                dst[d * 192 + e] = acc[dt][et][i];
            }
        }
}

// ---------------- K2b: reduce partials -> S ----------------
__global__ __launch_bounds__(256) void k_sreduce(const float* __restrict__ Sp, float* __restrict__ S, int KS)
{
    int idx = blockIdx.x * 256 + threadIdx.x;
    int b = idx / 36864, de = idx % 36864;
    float s = 0.f;
    for (int p = 0; p < KS; ++p) s += Sp[(size_t)(p * BB + b) * 36864 + de];
    S[(size_t)b * 36864 + de] = s;
}

// ---------------- K2c: softmax over d -> attT[b][e][d] bf16 ----------------
__global__ __launch_bounds__(64) void k_softmax(const float* __restrict__ S, u16* __restrict__ attT)
{
    const int bid = blockIdx.x;
    const int b = bid / 192, e = bid % 192;
    const int l = threadIdx.x;
    const float* Sb = S + (size_t)b * 36864 + e;
    float v0 = Sb[(size_t)(l * 3 + 0) * 192];
    float v1 = Sb[(size_t)(l * 3 + 1) * 192];
    float v2 = Sb[(size_t)(l * 3 + 2) * 192];
    float m = fmaxf(fmaxf(v0, v1), v2);
    #pragma unroll
    for (int s = 1; s < 64; s <<= 1) m = fmaxf(m, __shfl_xor(m, s, 64));
    v0 = __expf(v0 - m); v1 = __expf(v1 - m); v2 = __expf(v2 - m);
    float sum = v0 + v1 + v2;
    #pragma unroll
    for (int s = 1; s < 64; s <<= 1) sum += __shfl_xor(sum, s, 64);
    float inv = __fdividef(1.f, sum);
    u16* dst = attT + (size_t)b * 36864 + (size_t)e * 192 + l * 3;
    dst[0] = bf16r(v0 * inv); dst[1] = bf16r(v1 * inv); dst[2] = bf16r(v2 * inv);
}

// ---------------- K3: fused gate/sp + ch + LN + proj + store ----------------
// R14: 3 blocks/CU. Static LDS 53248 = dbuf 2x24576 + GT 4096; the tail's cat
// tile (50176) and epilogue-T (17408) overlay the same region. R8's proven
// 2-barrier chunk schedule (stage->pn first; end-__syncthreads drain hidden by
// co-residency). R13's reuse kept (each a_/bv feeds 2 MFMA). proj reads B from
// global pwb (L2-resident) -> no PW region, no barriers in the kt loop.
#define KF_GT  49152

__global__ __launch_bounds__(256, 3) void k_fused2(
    const float* __restrict__ x, const u16* __restrict__ x2cT,
    const u16* __restrict__ attT,
    const float* __restrict__ lnw, const float* __restrict__ lnb,
    const u16* __restrict__ pwb, const float* __restrict__ pb,
    float* __restrict__ out)
{
    __shared__ alignas(16) char LB[53248];
    const int t = threadIdx.x;
    const int l = t & 63, w = t >> 6;
    const int rg = w >> 1, cs = w & 1;          // 2 rg x 2 cs, 32 rows/wave
    const int b = blockIdx.x >> 8;
    const int n0 = (blockIdx.x & 255) << 6;
    const int l15 = l & 15, l4 = l >> 4, key = (l15 & 7) << 4;
    const int key3 = (l15 & 3) << 4;
    const size_t xrow0 = (size_t)(b * NN + n0) * CC;
    const char* cbase = (const char*)x2cT;      // x2cM = x2cT + 1572864 B (ws-contiguous)

    // per-lane inverse-swizzled global source offsets (chunk-invariant) + per-chunk stride
    int goff[6], gmul[6];
    #pragma unroll
    for (int it = 0; it < 6; ++it) {
        int q = it * 4096 + t * 16;             // dest byte in [CT|CM] 24576-chunk image
        if (q < 12288) {                        // CT: [m][384B row], key (m&7)<<4
            int m = q / 384, c = q % 384;
            goff[it] = b * 393216 + m * 384 + (c ^ ((m & 7) << 4));
            gmul[it] = 12288;                   // 32 m * 384 B per chunk
        } else {                                // CM: [d>>1][128B: d0|d1 x 32m], key ((d>>1)&7)<<4
            int qp = q - 12288;
            int r = qp >> 7, o = qp & 127;
            int op = o ^ ((r & 7) << 4);
            int d = r * 2 + (op >> 6);
            int m = (op & 63) >> 1;
            goff[it] = 1572864 + b * 393216 + d * 2048 + m * 2;
            gmul[it] = 64;                      // 32 m * 2 B per chunk
        }
    }

    // x1 A-fragments for 2 row-tiles (rows rg*32 + rt*16 + l15)
    short8 ax1[2][6];
    #pragma unroll
    for (int rt = 0; rt < 2; ++rt) {
        int row = rg * 32 + rt * 16 + l15;
        const float* src = &x[xrow0 + (size_t)row * CC + l4 * 8];
        #pragma unroll
        for (int k = 0; k < 6; ++k) {
            float4 v0 = ld4(src + k * 32), v1 = ld4(src + k * 32 + 4);
            ax1[rt][k] = as_s8(make_uint4(pk2(v0.x, v0.y), pk2(v0.z, v0.w), pk2(v1.x, v1.y), pk2(v1.z, v1.w)));
        }
    }

    // prologue: stage chunk 0 into buf 0
    #pragma unroll
    for (int it = 0; it < 6; ++it)
        gload16(cbase + goff[it], LB + it * 4096 + w * 1024);
    __syncthreads();

    f32x4 spa[2][6];
    #pragma unroll
    for (int rt = 0; rt < 2; ++rt)
        #pragma unroll
        for (int nt = 0; nt < 6; ++nt) spa[rt][nt] = (f32x4){0.f, 0.f, 0.f, 0.f};

    char* GTb = LB + KF_GT;                     // [64 rows][64B = 32 m bf16], key3-swizzled

    int p = 0;
    for (int mc = 0; mc < 32; ++mc) {
        // stage next chunk into other buffer (async; drained at chunk-end barrier)
        if (mc < 31) {
            const int pn = p ^ 1;
            #pragma unroll
            for (int it = 0; it < 6; ++it)
                gload16(cbase + goff[it] + (mc + 1) * gmul[it],
                        LB + pn * 24576 + it * 4096 + w * 1024);
        }
        const char* bufCT = LB + p * 24576;
        const char* bufCM = bufCT + 12288;

        // hoisted G2 B-frags (each feeds 2 MFMA); retired by the mid lgkmcnt(0)
        short8 bv[6];
        #pragma unroll
        for (int nt = 0; nt < 6; ++nt) {
            const int d = cs * 96 + nt * 16 + l15;
            const int rr = d >> 1;
            bv[nt] = *reinterpret_cast<const short8*>(
                bufCM + rr * 128 + ((((d & 1) * 64) + l4 * 16) ^ ((rr & 7) << 4)));
        }

        // G1' (swapped): C'[m = cs*16 + l4*4+i][r(rt) = rg*32+rt*16+l15],
        // each a_ read feeds 2 MFMA (rt = 0,1)
        f32x4 cp[2];
        cp[0] = (f32x4){0.f, 0.f, 0.f, 0.f};
        cp[1] = (f32x4){0.f, 0.f, 0.f, 0.f};
        #pragma unroll
        for (int kblk = 0; kblk < 6; ++kblk) {
            short8 a_ = *reinterpret_cast<const short8*>(
                bufCT + (cs * 16 + l15) * 384 + ((kblk * 64 + l4 * 16) ^ key));
            cp[0] = mfma16(a_, ax1[0][kblk], cp[0]);
            cp[1] = mfma16(a_, ax1[1][kblk], cp[1]);
        }
        // sigmoid + cvt_pk -> GT[row][m], rows rg*32+rt*16+l15, m = cs*16 + l4*4..+3
        #pragma unroll
        for (int rt = 0; rt < 2; ++rt) {
            float g0 = __fdividef(1.f, 1.f + __expf(-cp[rt][0]));
            float g1 = __fdividef(1.f, 1.f + __expf(-cp[rt][1]));
            float g2 = __fdividef(1.f, 1.f + __expf(-cp[rt][2]));
            float g3 = __fdividef(1.f, 1.f + __expf(-cp[rt][3]));
            uint2 gv; gv.x = pk2c(g0, g1); gv.y = pk2c(g2, g3);
            *reinterpret_cast<uint2*>(GTb + (rg * 32 + rt * 16 + l15) * 64 +
                ((cs * 32 + l4 * 8) ^ key3)) = gv;
        }
        // mid barrier: LDS-visibility only (staging loads stay in flight)
        asm volatile("s_waitcnt lgkmcnt(0)" ::: "memory");
        __builtin_amdgcn_s_barrier();
        __builtin_amdgcn_sched_barrier(0);
        // G2: sp[r][d] += gate[r][m] @ x2c[d][m]; each bv feeds 2 MFMA
        short8 ag[2];
        #pragma unroll
        for (int rt = 0; rt < 2; ++rt)
            ag[rt] = *reinterpret_cast<const short8*>(
                GTb + (rg * 32 + rt * 16 + l15) * 64 + ((l4 * 16) ^ key3));
        #pragma unroll
        for (int nt = 0; nt < 6; ++nt) {
            spa[0][nt] = mfma16(ag[0], bv[nt], spa[0][nt]);
            spa[1][nt] = mfma16(ag[1], bv[nt], spa[1][nt]);
        }
        __syncthreads();   // drains next-chunk staging + GT/dbuf reuse fence
        p ^= 1;
    }

    // Phase B: ch = x2 @ att (A and B from global; no LDS use)
    short8 ax2[2][6];
    #pragma unroll
    for (int rt = 0; rt < 2; ++rt) {
        int row = rg * 32 + rt * 16 + l15;
        const float* src = &x[xrow0 + (size_t)row * CC + DD + l4 * 8];
        #pragma unroll
        for (int k = 0; k < 6; ++k) {
            float4 v0 = ld4(src + k * 32), v1 = ld4(src + k * 32 + 4);
            ax2[rt][k] = as_s8(make_uint4(pk2(v0.x, v0.y), pk2(v0.z, v0.w), pk2(v1.x, v1.y), pk2(v1.z, v1.w)));
        }
    }
    f32x4 cha[2][6];
    #pragma unroll
    for (int rt = 0; rt < 2; ++rt)
        #pragma unroll
        for (int nt = 0; nt < 6; ++nt) cha[rt][nt] = (f32x4){0.f, 0.f, 0.f, 0.f};
    const u16* atb = attT + (size_t)b * 36864;
    #pragma unroll
    for (int nt = 0; nt < 6; ++nt) {
        int e = cs * 96 + nt * 16 + l15;
        #pragma unroll
        for (int k = 0; k < 6; ++k) {
            short8 bve = *reinterpret_cast<const short8*>(atb + (size_t)e * 192 + k * 32 + l4 * 8);
            cha[0][nt] = mfma16(ax2[0][k], bve, cha[0][nt]);
            cha[1][nt] = mfma16(ax2[1][k], bve, cha[1][nt]);
        }
    }
    // loop-end barrier already synced all LDS reads; cat overlays dbuf+GT now
    // write sp|ch -> cat LDS tile [64][392] u16
    #pragma unroll
    for (int rt = 0; rt < 2; ++rt)
        #pragma unroll
        for (int nt = 0; nt < 6; ++nt) {
            int d = cs * 96 + nt * 16 + l15;
            #pragma unroll
            for (int i = 0; i < 4; ++i) {
                int row = rg * 32 + rt * 16 + l4 * 4 + i;
                *reinterpret_cast<u16*>(LB + (row * 392 + d) * 2) = bf16r(spa[rt][nt][i]);
                *reinterpret_cast<u16*>(LB + (row * 392 + DD + d) * 2) = bf16r(cha[rt][nt][i]);
            }
        }
    __syncthreads();

    // LayerNorm: 4 thr/row on LDS cat (64 rows x 4 = 256 thr)
    {
        const int rowL = t >> 2, q = t & 3;
        char* lbase = LB + (rowL * 392 + q * 96) * 2;
        float s = 0.f, ss = 0.f;
        #pragma unroll
        for (int u = 0; u < 12; ++u) {
            uint4 pv = *reinterpret_cast<const uint4*>(lbase + u * 16);
            const unsigned int* pu = &pv.x;
            #pragma unroll
            for (int h = 0; h < 4; ++h) {
                float f0 = __uint_as_float(pu[h] << 16);
                float f1 = __uint_as_float(pu[h] & 0xFFFF0000u);
                s += f0 + f1; ss += f0 * f0 + f1 * f1;
            }
        }
        s += __shfl_xor(s, 1, 4);  s += __shfl_xor(s, 2, 4);
        ss += __shfl_xor(ss, 1, 4); ss += __shfl_xor(ss, 2, 4);
        float mu = s * (1.f / 384.f);
        float var = ss * (1.f / 384.f) - mu * mu;
        float rs = rsqrtf(var + 1e-5f);
        const int c0 = q * 96;
        #pragma unroll
        for (int u = 0; u < 12; ++u) {
            uint4 pv = *reinterpret_cast<const uint4*>(lbase + u * 16);
            const unsigned int* pu = &pv.x;
            float4 w0 = ld4(&lnw[c0 + u * 8]), w1 = ld4(&lnw[c0 + u * 8 + 4]);
            float4 b0 = ld4(&lnb[c0 + u * 8]), b1 = ld4(&lnb[c0 + u * 8 + 4]);
            float f[8];
            #pragma unroll
            for (int h = 0; h < 4; ++h) {
                f[2 * h]     = __uint_as_float(pu[h] << 16);
                f[2 * h + 1] = __uint_as_float(pu[h] & 0xFFFF0000u);
            }
            f[0] = (f[0] - mu) * rs * w0.x + b0.x; f[1] = (f[1] - mu) * rs * w0.y + b0.y;
            f[2] = (f[2] - mu) * rs * w0.z + b0.z; f[3] = (f[3] - mu) * rs * w0.w + b0.w;
            f[4] = (f[4] - mu) * rs * w1.x + b1.x; f[5] = (f[5] - mu) * rs * w1.y + b1.y;
            f[6] = (f[6] - mu) * rs * w1.z + b1.z; f[7] = (f[7] - mu) * rs * w1.w + b1.w;
            *reinterpret_cast<uint4*>(lbase + u * 16) =
                make_uint4(pk2c(f[0], f[1]), pk2c(f[2], f[3]), pk2c(f[4], f[5]), pk2c(f[6], f[7]));
        }
    }
    __syncthreads();

    // proj: 12 k-tiles, A from LDS cat, B straight from global pwb (L2-resident);
    // no barriers inside the loop
    f32x4 pacc[2][12];
    #pragma unroll
    for (int rt = 0; rt < 2; ++rt)
        #pragma unroll
        for (int nt = 0; nt < 12; ++nt) pacc[rt][nt] = (f32x4){0.f, 0.f, 0.f, 0.f};
    for (int kt = 0; kt < 12; ++kt) {
        short8 av[2];
        #pragma unroll
        for (int rt = 0; rt < 2; ++rt) {
            int row = rg * 32 + rt * 16 + l15;
            av[rt] = *reinterpret_cast<const short8*>(LB + (row * 392 + kt * 32 + l4 * 8) * 2);
        }
        const u16* pwk = pwb + kt * 32 + l4 * 8;
        #pragma unroll
        for (int nt = 0; nt < 12; ++nt) {
            int o = cs * 192 + nt * 16 + l15;
            short8 bvp = as_s8(*reinterpret_cast<const uint4*>(pwk + (size_t)o * CC));
            pacc[0][nt] = mfma16(av[0], bvp, pacc[0][nt]);
            pacc[1][nt] = mfma16(av[1], bvp, pacc[1][nt]);
        }
    }
    __syncthreads();   // all cat reads done; T overlays cat region

    // epilogue: 6 o-slices of 64, LDS transpose for full-line stores
    float* T = reinterpret_cast<float*>(LB);
    for (int os = 0; os < 6; ++os) {
        if (cs == (os >= 3 ? 1 : 0)) {
            const int nt0 = (os % 3) * 4;
            #pragma unroll
            for (int nt = 0; nt < 4; ++nt) {
                int o_l = nt * 16 + l15;
                float bias = pb[os * 64 + o_l];
                #pragma unroll
                for (int rt = 0; rt < 2; ++rt)
                    #pragma unroll
                    for (int i = 0; i < 4; ++i)
                        T[o_l * 68 + rg * 32 + rt * 16 + l4 * 4 + i] = pacc[rt][nt0 + nt][i] + bias;
            }
        }
        __syncthreads();
        {
            const int o_l = t >> 2, nq = t & 3;
            const size_t gbase = (size_t)(b * CC + os * 64 + o_l) * NN + n0 + nq * 16;
            #pragma unroll
            for (int j = 0; j < 4; ++j) {
                float4 v = *reinterpret_cast<const float4*>(&T[o_l * 68 + nq * 16 + j * 4]);
                *reinterpret_cast<float4*>(&out[gbase + j * 4]) = v;
            }
        }
        __syncthreads();
    }
}

extern "C" void kernel_launch(void* const* d_in, const int* in_sizes, int n_in,
                              void* d_out, int out_size, void* d_ws, size_t ws_size,
                              hipStream_t stream)
{
    (void)in_sizes; (void)n_in; (void)out_size;
    const float* x   = (const float*)d_in[0];
    const float* cw  = (const float*)d_in[1];
    const float* cb  = (const float*)d_in[2];
    const float* lnw = (const float*)d_in[3];
    const float* lnb = (const float*)d_in[4];
    const float* pwm = (const float*)d_in[5];
    const float* pbv = (const float*)d_in[6];
    float* out = (float*)d_out;
    char* w0 = (char*)d_ws;

    u16* x2cT = (u16*)(w0);                       // 1572864 (x2cM MUST follow contiguously)
    u16* x2cM = (u16*)(w0 + 1572864);             // 1572864
    u16* attT = (u16*)(w0 + 3145728);             // 294912
    u16* pwb  = (u16*)(w0 + 3440640);             // 294912
    u16* cwb  = (u16*)(w0 + 3735552);             // 1179648
    float* Cp2 = (float*)(w0 + 4915200);          // 6291456
    float* Sp  = (float*)(w0 + 11206656);         // 18874368 (KS=32)
    float* Sf  = (float*)(w0 + 30081024);         // 589824

    int KS = 32;
    if (ws_size >= (size_t)68419584) {            // Sp64 at 30670848, 37748736 B
        KS = 64;
        Sp = (float*)(w0 + 30670848);
    }
    const int nkt = (NN / KS) / 32;

    hipLaunchKernelGGL(k_prep,    dim3(144),      dim3(256), 0, stream, pwm, pwb);
    hipLaunchKernelGGL(k_prepw,   dim3(288),      dim3(256), 0, stream, cw, cwb);
    hipLaunchKernelGGL(k_conv,    dim3(512),      dim3(256), 0, stream, x, cwb, Cp2);
    hipLaunchKernelGGL(k_convred, dim3(64),       dim3(256), 0, stream, Cp2, cb, x2cT, x2cM);
    hipLaunchKernelGGL(k_S,       dim3(BB * KS),  dim3(512), 0, stream, x, Sp, KS, nkt);
    hipLaunchKernelGGL(k_sreduce, dim3(576),      dim3(256), 0, stream, Sp, Sf, KS);
    hipLaunchKernelGGL(k_softmax, dim3(BB * 192), dim3(64),  0, stream, Sf, attT);
    hipLaunchKernelGGL(k_fused2,  dim3(1024),     dim3(256), 0, stream,
                       x, x2cT, attT, lnw, lnb, pwb, pbv, out);
}

// Round 15
// 274.004 us; speedup vs baseline: 1.2448x; 1.2448x over previous
//
#include <hip/hip_runtime.h>
#include <hip/hip_bf16.h>

#define BB 4
#define NN 16384
#define CC 384
#define DD 192
#define MM 1024

typedef __attribute__((ext_vector_type(8))) short short8;
typedef __attribute__((ext_vector_type(4))) float f32x4;
typedef unsigned short u16;

__device__ __forceinline__ float4 ld4(const float* p) { return *reinterpret_cast<const float4*>(p); }

__device__ __forceinline__ u16 bf16r(float f) {
    unsigned int u = __float_as_uint(f);
    return (u16)((u + 0x7FFFu + ((u >> 16) & 1u)) >> 16);
}
__device__ __forceinline__ unsigned int pk2(float a, float b) {
    return (unsigned int)bf16r(a) | ((unsigned int)bf16r(b) << 16);
}
// packed RNE f32x2 -> bf16x2 (lowers to v_cvt_pk_bf16_f32)
__device__ __forceinline__ unsigned int pk2c(float a, float b) {
    __hip_bfloat162 h = __float22bfloat162_rn(make_float2(a, b));
    union { __hip_bfloat162 h2; unsigned int u; } c; c.h2 = h; return c.u;
}
__device__ __forceinline__ short8 as_s8(uint4 v) {
    union { uint4 u; short8 s; } x; x.u = v; return x.s;
}
__device__ __forceinline__ f32x4 mfma16(short8 a, short8 b, f32x4 c) {
    return __builtin_amdgcn_mfma_f32_16x16x32_bf16(a, b, c, 0, 0, 0);
}
// async global->LDS, 16B per lane; LDS dest = wave-uniform base + lane*16
__device__ __forceinline__ void gload16(const void* g, void* l) {
    __builtin_amdgcn_global_load_lds(
        (const __attribute__((address_space(1))) void*)g,
        (__attribute__((address_space(3))) void*)l, 16, 0, 0);
}

// ---------------- K0a: proj_w fp32 -> bf16 ----------------
__global__ __launch_bounds__(256) void k_prep(const float* __restrict__ pw, u16* __restrict__ pwb)
{
    int i = blockIdx.x * 256 + threadIdx.x;
    float4 v = ld4(&pw[i * 4]);
    uint2 o; o.x = pk2(v.x, v.y); o.y = pk2(v.z, v.w);
    reinterpret_cast<uint2*>(pwb)[i] = o;
}

// ---------------- K0b: conv_w -> cwb[k8][o][8] bf16, k = px*192 + i ----------------
__global__ __launch_bounds__(256) void k_prepw(const float* __restrict__ cw, u16* __restrict__ cwb)
{
    int idx = blockIdx.x * 256 + threadIdx.x;
    int k8 = idx / 192, o = idx % 192;
    int px = k8 / 24;
    int i0 = (k8 % 24) * 8;
    float f[8];
    #pragma unroll
    for (int e = 0; e < 8; ++e) f[e] = cw[(size_t)(o * 192 + i0 + e) * 16 + px];
    uint4 v = make_uint4(pk2(f[0], f[1]), pk2(f[2], f[3]), pk2(f[4], f[5]), pk2(f[6], f[7]));
    reinterpret_cast<uint4*>(cwb)[idx] = v;
}

// ---------------- K1: conv via MFMA, px-split x2 -> partials Cp2[s][P][o] ----------------
__global__ __launch_bounds__(256) void k_conv(const float* __restrict__ x,
                                              const u16* __restrict__ cwb,
                                              float* __restrict__ Cp2)
{
    const int bid = blockIdx.x;
    const int s = bid >> 8, pt = bid & 255;
    const int b = pt >> 6;
    const int m0 = (pt & 63) * 16;
    const int P0 = pt * 16;
    const int t = threadIdx.x;
    const int l = t & 63, w = t >> 6;
    const int l15 = l & 15, l4 = l >> 4;
    const int o0 = w * 48;

    const int m = m0 + l15;
    const int ph = m >> 5, pw_ = m & 31;
    const float* xp = x + ((size_t)(b * NN) + ph * 512 + pw_ * 4) * CC + DD;

    f32x4 acc[3];
    #pragma unroll
    for (int ft = 0; ft < 3; ++ft) acc[ft] = (f32x4){0.f, 0.f, 0.f, 0.f};

    for (int kt = 0; kt < 48; ++kt) {
        const int px = s * 8 + kt / 6;
        const int i0 = (kt % 6) * 32;
        const int kh = px >> 2, kw = px & 3;
        const float* src = xp + (size_t)(kh * 128 + kw) * CC + i0 + l4 * 8;
        float4 v0 = ld4(src), v1 = ld4(src + 4);
        short8 av = as_s8(make_uint4(pk2(v0.x, v0.y), pk2(v0.z, v0.w), pk2(v1.x, v1.y), pk2(v1.z, v1.w)));
        const int k8g = px * 24 + (kt % 6) * 4 + l4;
        #pragma unroll
        for (int ft = 0; ft < 3; ++ft) {
            int o = o0 + ft * 16 + l15;
            short8 bv = as_s8(*reinterpret_cast<const uint4*>(cwb + (size_t)(k8g * 192 + o) * 8));
            acc[ft] = mfma16(av, bv, acc[ft]);
        }
    }
    #pragma unroll
    for (int ft = 0; ft < 3; ++ft)
        #pragma unroll
        for (int i = 0; i < 4; ++i)
            Cp2[(size_t)(s * 4096 + P0 + l4 * 4 + i) * 192 + o0 + ft * 16 + l15] = acc[ft][i];
}

// ---------------- K1b: reduce px-splits + bias -> x2cT[m][d], x2cM[d][m] bf16 ----------------
__global__ __launch_bounds__(256) void k_convred(const float* __restrict__ Cp2,
                                                 const float* __restrict__ cb,
                                                 u16* __restrict__ x2cT,
                                                 u16* __restrict__ x2cM)
{
    __shared__ u16 T[64 * 194];
    const int bid = blockIdx.x;
    const int b = bid >> 4, mc = bid & 15;
    const int P0 = b * 1024 + mc * 64;
    const int t = threadIdx.x;
    #pragma unroll
    for (int j = 0; j < 12; ++j) {
        int idx = j * 256 + t;
        int row = idx / 48, c4 = idx % 48;
        float4 v0 = ld4(&Cp2[(size_t)(P0 + row) * 192 + c4 * 4]);
        float4 v1 = ld4(&Cp2[(size_t)(4096 + P0 + row) * 192 + c4 * 4]);
        float4 bb = ld4(&cb[c4 * 4]);
        float r0 = v0.x + v1.x + bb.x, r1 = v0.y + v1.y + bb.y;
        float r2 = v0.z + v1.z + bb.z, r3 = v0.w + v1.w + bb.w;
        u16 h0 = bf16r(r0), h1 = bf16r(r1), h2 = bf16r(r2), h3 = bf16r(r3);
        uint2 ov; ov.x = (unsigned int)h0 | ((unsigned int)h1 << 16);
        ov.y = (unsigned int)h2 | ((unsigned int)h3 << 16);
        *reinterpret_cast<uint2*>(x2cT + (size_t)(P0 + row) * 192 + c4 * 4) = ov;
        T[row * 194 + c4 * 4 + 0] = h0; T[row * 194 + c4 * 4 + 1] = h1;
        T[row * 194 + c4 * 4 + 2] = h2; T[row * 194 + c4 * 4 + 3] = h3;
    }
    __syncthreads();
    #pragma unroll
    for (int j = 0; j < 6; ++j) {
        int u = j * 256 + t;
        int o = u >> 3, m8 = (u & 7) * 8;
        unsigned int pk[4];
        #pragma unroll
        for (int q = 0; q < 4; ++q) {
            u16 a = T[(m8 + q * 2) * 194 + o];
            u16 c = T[(m8 + q * 2 + 1) * 194 + o];
            pk[q] = (unsigned int)a | ((unsigned int)c << 16);
        }
        *reinterpret_cast<uint4*>(x2cM + ((size_t)(b * DD + o) * MM) + mc * 64 + m8) =
            make_uint4(pk[0], pk[1], pk[2], pk[3]);
    }
}

// ---------------- K2: S partials via bf16 hi/lo MFMA ----------------
// R15: staging vectorized — each thread owns a contiguous k-octet per c and
// emits 2 x ds_write_b128 (hi, lo) instead of 48 scalar b16 writes per chunk.
// Layout/XOR identical to before; read side unchanged.
__global__ __launch_bounds__(512) void k_S(const float* __restrict__ x, float* __restrict__ Sp,
                                           int KS, int nkt)
{
    __shared__ char LS[384 * 128];
    const int bid = blockIdx.x;
    const int b = bid / KS, ks = bid % KS;
    const int n0 = ks * (NN / KS);
    const int t = threadIdx.x;
    const int l = t & 63, w = t >> 6;
    const int rg = w >> 2, cs = w & 3;
    const int l15 = l & 15, l4 = l >> 4, key = (l15 & 7) << 4;

    const int c0 = (t & 127) * 3;
    const int krow = t >> 7;                    // k-octet base = krow*8

    f32x4 acc[6][3];
    #pragma unroll
    for (int dt = 0; dt < 6; ++dt)
        #pragma unroll
        for (int et = 0; et < 3; ++et) acc[dt][et] = (f32x4){0.f, 0.f, 0.f, 0.f};

    for (int kt = 0; kt < nkt; ++kt) {
        __syncthreads();
        #pragma unroll
        for (int j = 0; j < 3; ++j) {
            const int c = c0 + j;
            const float* src = &x[(size_t)(b * NN + n0 + kt * 32 + krow * 8) * CC + c];
            unsigned int hi4[4], lo4[4];
            #pragma unroll
            for (int q = 0; q < 4; ++q) {
                float va = src[(size_t)(2 * q) * CC];
                float vb = src[(size_t)(2 * q + 1) * CC];
                u16 ha = bf16r(va);
                u16 la = bf16r(va - __uint_as_float(((unsigned int)ha) << 16));
                u16 hb = bf16r(vb);
                u16 lb = bf16r(vb - __uint_as_float(((unsigned int)hb) << 16));
                hi4[q] = (unsigned int)ha | ((unsigned int)hb << 16);
                lo4[q] = (unsigned int)la | ((unsigned int)lb << 16);
            }
            const int ck = (c & 7) << 4;
            *reinterpret_cast<uint4*>(LS + c * 128 + ((krow * 16) ^ ck)) =
                make_uint4(hi4[0], hi4[1], hi4[2], hi4[3]);
            *reinterpret_cast<uint4*>(LS + c * 128 + ((64 + krow * 16) ^ ck)) =
                make_uint4(lo4[0], lo4[1], lo4[2], lo4[3]);
        }
        __syncthreads();
        short8 bf[3][2];
        #pragma unroll
        for (int et = 0; et < 3; ++et) {
            int c = 192 + cs * 48 + et * 16 + l15;
            #pragma unroll
            for (int hl = 0; hl < 2; ++hl)
                bf[et][hl] = *reinterpret_cast<const short8*>(LS + c * 128 + ((hl * 64 + l4 * 16) ^ key));
        }
        #pragma unroll
        for (int dt = 0; dt < 6; ++dt) {
            int c = rg * 96 + dt * 16 + l15;
            short8 ah = *reinterpret_cast<const short8*>(LS + c * 128 + ((l4 * 16) ^ key));
            short8 al = *reinterpret_cast<const short8*>(LS + c * 128 + ((64 + l4 * 16) ^ key));
            #pragma unroll
            for (int et = 0; et < 3; ++et) {
                acc[dt][et] = mfma16(ah, bf[et][0], acc[dt][et]);
                acc[dt][et] = mfma16(ah, bf[et][1], acc[dt][et]);
                acc[dt][et] = mfma16(al, bf[et][0], acc[dt][et]);
            }
        }
    }
    float* dst = Sp + (size_t)(ks * BB + b) * 36864;
    #pragma unroll
    for (int dt = 0; dt < 6; ++dt)
        #pragma unroll
        for (int et = 0; et < 3; ++et) {
            int e = cs * 48 + et * 16 + l15;
            #pragma unroll
            for (int i = 0; i < 4; ++i) {
                int d = rg * 96 + dt * 16 + l4 * 4 + i;
                dst[d * 192 + e] = acc[dt][et][i];
            }
        }
}

// ---------------- K2b: reduce partials -> S ----------------
__global__ __launch_bounds__(256) void k_sreduce(const float* __restrict__ Sp, float* __restrict__ S, int KS)
{
    int idx = blockIdx.x * 256 + threadIdx.x;
    int b = idx / 36864, de = idx % 36864;
    float s = 0.f;
    for (int p = 0; p < KS; ++p) s += Sp[(size_t)(p * BB + b) * 36864 + de];
    S[(size_t)b * 36864 + de] = s;
}

// ---------------- K2c: softmax over d -> attT[b][e][d] bf16 ----------------
__global__ __launch_bounds__(64) void k_softmax(const float* __restrict__ S, u16* __restrict__ attT)
{
    const int bid = blockIdx.x;
    const int b = bid / 192, e = bid % 192;
    const int l = threadIdx.x;
    const float* Sb = S + (size_t)b * 36864 + e;
    float v0 = Sb[(size_t)(l * 3 + 0) * 192];
    float v1 = Sb[(size_t)(l * 3 + 1) * 192];
    float v2 = Sb[(size_t)(l * 3 + 2) * 192];
    float m = fmaxf(fmaxf(v0, v1), v2);
    #pragma unroll
    for (int s = 1; s < 64; s <<= 1) m = fmaxf(m, __shfl_xor(m, s, 64));
    v0 = __expf(v0 - m); v1 = __expf(v1 - m); v2 = __expf(v2 - m);
    float sum = v0 + v1 + v2;
    #pragma unroll
    for (int s = 1; s < 64; s <<= 1) sum += __shfl_xor(sum, s, 64);
    float inv = __fdividef(1.f, sum);
    u16* dst = attT + (size_t)b * 36864 + (size_t)e * 192 + l * 3;
    dst[0] = bf16r(v0 * inv); dst[1] = bf16r(v1 * inv); dst[2] = bf16r(v2 * inv);
}

// ---------------- K3: fused gate/sp + ch + LN + proj + store (R11 proven-best) ----------------
#define KF_PW  50176
#define KF_GT  73728

__global__ __launch_bounds__(512, 4) void k_fused2(
    const float* __restrict__ x, const u16* __restrict__ x2cT,
    const u16* __restrict__ attT,
    const float* __restrict__ lnw, const float* __restrict__ lnb,
    const u16* __restrict__ pwb, const float* __restrict__ pb,
    float* __restrict__ out)
{
    __shared__ alignas(16) char LB[77824];      // main: 3x24576 bufs + GT 4096 | post: cat 50176 + PW 24576
    const int t = threadIdx.x;
    const int l = t & 63, w = t >> 6;
    const int rg = w >> 1, cs = w & 1;          // 4 rg x 2 cs
    const int b = blockIdx.x >> 8;
    const int n0 = (blockIdx.x & 255) << 6;
    const int l15 = l & 15, l4 = l >> 4, key = (l15 & 7) << 4;
    const int key3 = (l15 & 3) << 4;
    const size_t xrow0 = (size_t)(b * NN + n0) * CC;
    const char* cbase = (const char*)x2cT;      // x2cM = x2cT + 1572864 B (ws-contiguous)

    // per-lane inverse-swizzled global source offsets (chunk-invariant) + per-chunk stride
    int goff[3], gmul[3];
    #pragma unroll
    for (int it = 0; it < 3; ++it) {
        int q = it * 8192 + w * 1024 + l * 16;  // dest byte in [CT|CM] 24576-chunk image
        if (q < 12288) {                        // CT: [m][384B row], key (m&7)<<4
            int m = q / 384, c = q % 384;
            goff[it] = b * 393216 + m * 384 + (c ^ ((m & 7) << 4));
            gmul[it] = 12288;                   // 32 m * 384 B per chunk
        } else {                                // CM: [d>>1][128B: d0|d1 x 32m], key ((d>>1)&7)<<4
            int qp = q - 12288;
            int r = qp >> 7, o = qp & 127;
            int op = o ^ ((r & 7) << 4);
            int d = r * 2 + (op >> 6);
            int m = (op & 63) >> 1;
            goff[it] = 1572864 + b * 393216 + d * 2048 + m * 2;
            gmul[it] = 64;                      // 32 m * 2 B per chunk
        }
    }

    // x1 A-fragments (rows rg*16+l15); layout identity: also usable as G1' B-frags
    short8 ax1[6];
    {
        int row = rg * 16 + l15;
        const float* src = &x[xrow0 + (size_t)row * CC + l4 * 8];
        #pragma unroll
        for (int k = 0; k < 6; ++k) {
            float4 v0 = ld4(src + k * 32), v1 = ld4(src + k * 32 + 4);
            ax1[k] = as_s8(make_uint4(pk2(v0.x, v0.y), pk2(v0.z, v0.w), pk2(v1.x, v1.y), pk2(v1.z, v1.w)));
        }
    }

    // prologue: stage chunk 0 -> bufA, chunk 1 -> bufB (6 loads in flight)
    char* bA = LB;
    char* bB = LB + 24576;
    char* bC = LB + 49152;
    #pragma unroll
    for (int it = 0; it < 3; ++it)
        gload16(cbase + goff[it], bA + it * 8192 + w * 1024);
    #pragma unroll
    for (int it = 0; it < 3; ++it)
        gload16(cbase + goff[it] + gmul[it], bB + it * 8192 + w * 1024);

    f32x4 spa[6];
    #pragma unroll
    for (int nt = 0; nt < 6; ++nt) spa[nt] = (f32x4){0.f, 0.f, 0.f, 0.f};

    char* GTb = LB + KF_GT;                     // [64 rows][64B = 32 m bf16], key3-swizzled

    for (int mc = 0; mc < 32; ++mc) {
        // wait own stage(mc) loads (keep stage(mc+1)'s 3 in flight), then sync waves
        if (mc < 31) asm volatile("s_waitcnt vmcnt(3)" ::: "memory");
        else         asm volatile("s_waitcnt vmcnt(0)" ::: "memory");
        __builtin_amdgcn_s_barrier();
        __builtin_amdgcn_sched_barrier(0);
        // issue stage(mc+2) into bC (its last readers finished before this barrier)
        if (mc + 2 < 32) {
            #pragma unroll
            for (int it = 0; it < 3; ++it)
                gload16(cbase + goff[it] + (mc + 2) * gmul[it], bC + it * 8192 + w * 1024);
        }
        const char* bufCT = bA;
        const char* bufCM = bA + 12288;

        // G1' (swapped, non-redundant): C'[m = cs*16 + l4*4+i][r = l15], 6 MFMA
        f32x4 cp = (f32x4){0.f, 0.f, 0.f, 0.f};
        #pragma unroll
        for (int kblk = 0; kblk < 6; ++kblk) {
            short8 a_ = *reinterpret_cast<const short8*>(
                bufCT + (cs * 16 + l15) * 384 + ((kblk * 64 + l4 * 16) ^ key));
            cp = mfma16(a_, ax1[kblk], cp);
        }
        // sigmoid + cvt_pk -> GT[row = rg*16+l15][m = cs*16 + l4*4 .. +3]
        {
            float g0 = __fdividef(1.f, 1.f + __expf(-cp[0]));
            float g1 = __fdividef(1.f, 1.f + __expf(-cp[1]));
            float g2 = __fdividef(1.f, 1.f + __expf(-cp[2]));
            float g3 = __fdividef(1.f, 1.f + __expf(-cp[3]));
            uint2 gv; gv.x = pk2c(g0, g1); gv.y = pk2c(g2, g3);
            *reinterpret_cast<uint2*>(GTb + (rg * 16 + l15) * 64 +
                ((cs * 32 + l4 * 8) ^ key3)) = gv;
        }
        // mid barrier: LDS-visibility only (staging loads stay in flight)
        asm volatile("s_waitcnt lgkmcnt(0)" ::: "memory");
        __builtin_amdgcn_s_barrier();
        __builtin_amdgcn_sched_barrier(0);
        // G2: sp[r][d] += gate[r][m] @ x2c[d][m], 6 MFMA
        short8 ag = *reinterpret_cast<const short8*>(
            GTb + (rg * 16 + l15) * 64 + ((l4 * 16) ^ key3));
        #pragma unroll
        for (int nt = 0; nt < 6; ++nt) {
            const int d = cs * 96 + nt * 16 + l15;
            const int rr = d >> 1;
            short8 bv = *reinterpret_cast<const short8*>(
                bufCM + rr * 128 + ((((d & 1) * 64) + l4 * 16) ^ ((rr & 7) << 4)));
            spa[nt] = mfma16(ag, bv, spa[nt]);
        }
        // rotate buffers (no barrier here — next iteration's barrier covers reuse;
        // GT reuse is fenced by the same next-chunk mid barrier pair)
        char* tmp = bA; bA = bB; bB = bC; bC = tmp;
    }

    // Phase B: ch = x2 @ att (A and B from global; no LDS use yet)
    short8 ax2[6];
    {
        int row = rg * 16 + l15;
        const float* src = &x[xrow0 + (size_t)row * CC + DD + l4 * 8];
        #pragma unroll
        for (int k = 0; k < 6; ++k) {
            float4 v0 = ld4(src + k * 32), v1 = ld4(src + k * 32 + 4);
            ax2[k] = as_s8(make_uint4(pk2(v0.x, v0.y), pk2(v0.z, v0.w), pk2(v1.x, v1.y), pk2(v1.z, v1.w)));
        }
    }
    f32x4 cha[6];
    #pragma unroll
    for (int nt = 0; nt < 6; ++nt) cha[nt] = (f32x4){0.f, 0.f, 0.f, 0.f};
    const u16* atb = attT + (size_t)b * 36864;
    #pragma unroll
    for (int nt = 0; nt < 6; ++nt) {
        int e = cs * 96 + nt * 16 + l15;
        #pragma unroll
        for (int k = 0; k < 6; ++k) {
            short8 bv = *reinterpret_cast<const short8*>(atb + (size_t)e * 192 + k * 32 + l4 * 8);
            cha[nt] = mfma16(ax2[k], bv, cha[nt]);
        }
    }
    __syncthreads();   // all waves done reading bufs/GT before cat overlays them

    // write sp|ch -> cat LDS tile [64][392] u16 (overlays dead bufs)
    #pragma unroll
    for (int nt = 0; nt < 6; ++nt) {
        int d = cs * 96 + nt * 16 + l15;
        #pragma unroll
        for (int i = 0; i < 4; ++i) {
            int row = rg * 16 + l4 * 4 + i;
            *reinterpret_cast<u16*>(LB + (row * 392 + d) * 2) = bf16r(spa[nt][i]);
            *reinterpret_cast<u16*>(LB + (row * 392 + DD + d) * 2) = bf16r(cha[nt][i]);
        }
    }
    __syncthreads();

    // LayerNorm: 8 thr/row on LDS cat
    {
        const int rowL = t >> 3, q = t & 7;
        char* lbase = LB + rowL * 784 + q * 96;
        float s = 0.f, ss = 0.f;
        #pragma unroll
        for (int u = 0; u < 6; ++u) {
            uint4 pv = *reinterpret_cast<const uint4*>(lbase + u * 16);
            const unsigned int* pu = &pv.x;
            #pragma unroll
            for (int h = 0; h < 4; ++h) {
                float f0 = __uint_as_float(pu[h] << 16);
                float f1 = __uint_as_float(pu[h] & 0xFFFF0000u);
                s += f0 + f1; ss += f0 * f0 + f1 * f1;
            }
        }
        s += __shfl_xor(s, 1, 8);  s += __shfl_xor(s, 2, 8);  s += __shfl_xor(s, 4, 8);
        ss += __shfl_xor(ss, 1, 8); ss += __shfl_xor(ss, 2, 8); ss += __shfl_xor(ss, 4, 8);
        float mu = s * (1.f / 384.f);
        float var = ss * (1.f / 384.f) - mu * mu;
        float rs = rsqrtf(var + 1e-5f);
        const int c0 = q * 48;
        #pragma unroll
        for (int u = 0; u < 6; ++u) {
            uint4 pv = *reinterpret_cast<const uint4*>(lbase + u * 16);
            const unsigned int* pu = &pv.x;
            float4 w0 = ld4(&lnw[c0 + u * 8]), w1 = ld4(&lnw[c0 + u * 8 + 4]);
            float4 b0 = ld4(&lnb[c0 + u * 8]), b1 = ld4(&lnb[c0 + u * 8 + 4]);
            float f[8];
            #pragma unroll
            for (int h = 0; h < 4; ++h) {
                f[2 * h]     = __uint_as_float(pu[h] << 16);
                f[2 * h + 1] = __uint_as_float(pu[h] & 0xFFFF0000u);
            }
            f[0] = (f[0] - mu) * rs * w0.x + b0.x; f[1] = (f[1] - mu) * rs * w0.y + b0.y;
            f[2] = (f[2] - mu) * rs * w0.z + b0.z; f[3] = (f[3] - mu) * rs * w0.w + b0.w;
            f[4] = (f[4] - mu) * rs * w1.x + b1.x; f[5] = (f[5] - mu) * rs * w1.y + b1.y;
            f[6] = (f[6] - mu) * rs * w1.z + b1.z; f[7] = (f[7] - mu) * rs * w1.w + b1.w;
            *reinterpret_cast<uint4*>(lbase + u * 16) =
                make_uint4(pk2c(f[0], f[1]), pk2c(f[2], f[3]), pk2c(f[4], f[5]), pk2c(f[6], f[7]));
        }
    }

    // proj: 12 k-tiles, PW staged in LDS (region disjoint from cat)
    f32x4 pacc[12];
    #pragma unroll
    for (int nt = 0; nt < 12; ++nt) pacc[nt] = (f32x4){0.f, 0.f, 0.f, 0.f};
    for (int kt = 0; kt < 12; ++kt) {
        __syncthreads();
        #pragma unroll
        for (int j = 0; j < 3; ++j) {
            int u = j * 512 + t;
            int o = u >> 2, c8 = (u & 3) * 8;
            uint4 pv = *reinterpret_cast<const uint4*>(pwb + (size_t)o * CC + kt * 32 + c8);
            *reinterpret_cast<uint4*>(LB + KF_PW + (((o * 32 + c8) * 2) ^ ((o & 7) << 4))) = pv;
        }
        __syncthreads();
        short8 av = *reinterpret_cast<const short8*>(
            LB + ((rg * 16 + l15) * 392 + kt * 32 + l4 * 8) * 2);
        #pragma unroll
        for (int nt = 0; nt < 12; ++nt) {
            int o = cs * 192 + nt * 16 + l15;
            short8 bvp = *reinterpret_cast<const short8*>(
                LB + KF_PW + (((o * 32 + l4 * 8) * 2) ^ ((o & 7) << 4)));
            pacc[nt] = mfma16(av, bvp, pacc[nt]);
        }
    }
    __syncthreads();

    // epilogue: 6 o-slices of 64, LDS transpose (in dead PW region) for full-line stores
    float* T = reinterpret_cast<float*>(LB + KF_PW);
    for (int os = 0; os < 6; ++os) {
        if (cs == (os >= 3 ? 1 : 0)) {
            const int nt0 = (os % 3) * 4;
            #pragma unroll
            for (int nt = 0; nt < 4; ++nt) {
                int o_l = nt * 16 + l15;
                float bias = pb[os * 64 + o_l];
                #pragma unroll
                for (int i = 0; i < 4; ++i)
                    T[o_l * 68 + rg * 16 + l4 * 4 + i] = pacc[nt0 + nt][i] + bias;
            }
        }
        __syncthreads();
        {
            const int o_l = t >> 3, nq = t & 7;
            const size_t gbase = (size_t)(b * CC + os * 64 + o_l) * NN + n0 + nq * 8;
            float4 v0 = *reinterpret_cast<const float4*>(&T[o_l * 68 + nq * 8]);
            float4 v1 = *reinterpret_cast<const float4*>(&T[o_l * 68 + nq * 8 + 4]);
            *reinterpret_cast<float4*>(&out[gbase]) = v0;
            *reinterpret_cast<float4*>(&out[gbase + 4]) = v1;
        }
        __syncthreads();
    }
}

extern "C" void kernel_launch(void* const* d_in, const int* in_sizes, int n_in,
                              void* d_out, int out_size, void* d_ws, size_t ws_size,
                              hipStream_t stream)
{
    (void)in_sizes; (void)n_in; (void)out_size;
    const float* x   = (const float*)d_in[0];
    const float* cw  = (const float*)d_in[1];
    const float* cb  = (const float*)d_in[2];
    const float* lnw = (const float*)d_in[3];
    const float* lnb = (const float*)d_in[4];
    const float* pwm = (const float*)d_in[5];
    const float* pbv = (const float*)d_in[6];
    float* out = (float*)d_out;
    char* w0 = (char*)d_ws;

    u16* x2cT = (u16*)(w0);                       // 1572864 (x2cM MUST follow contiguously)
    u16* x2cM = (u16*)(w0 + 1572864);             // 1572864
    u16* attT = (u16*)(w0 + 3145728);             // 294912
    u16* pwb  = (u16*)(w0 + 3440640);             // 294912
    u16* cwb  = (u16*)(w0 + 3735552);             // 1179648
    float* Cp2 = (float*)(w0 + 4915200);          // 6291456
    float* Sp  = (float*)(w0 + 11206656);         // 18874368 (KS=32)
    float* Sf  = (float*)(w0 + 30081024);         // 589824

    int KS = 32;
    if (ws_size >= (size_t)68419584) {            // Sp64 at 30670848, 37748736 B
        KS = 64;
        Sp = (float*)(w0 + 30670848);
    }
    const int nkt = (NN / KS) / 32;

    hipLaunchKernelGGL(k_prep,    dim3(144),      dim3(256), 0, stream, pwm, pwb);
    hipLaunchKernelGGL(k_prepw,   dim3(288),      dim3(256), 0, stream, cw, cwb);
    hipLaunchKernelGGL(k_conv,    dim3(512),      dim3(256), 0, stream, x, cwb, Cp2);
    hipLaunchKernelGGL(k_convred, dim3(64),       dim3(256), 0, stream, Cp2, cb, x2cT, x2cM);
    hipLaunchKernelGGL(k_S,       dim3(BB * KS),  dim3(512), 0, stream, x, Sp, KS, nkt);
    hipLaunchKernelGGL(k_sreduce, dim3(576),      dim3(256), 0, stream, Sp, Sf, KS);
    hipLaunchKernelGGL(k_softmax, dim3(BB * 192), dim3(64),  0, stream, Sf, attT);
    hipLaunchKernelGGL(k_fused2,  dim3(1024),     dim3(512), 0, stream,
                       x, x2cT, attT, lnw, lnb, pwb, pbv, out);
}